// Round 8
// baseline (275.815 us; speedup 1.0000x reference)
//
#include <hip/hip_runtime.h>

// GAT layer: N=100000 nodes, E=1.6M edges, IN=128, H=4, F=16 (H*F=64)
// fp32 in/out. Pipeline:
//   gemm_att: h=x@W (register-blocked LDS GEMM, h stored bf16) + att_s/att_d
//   bcount/bscan:  coarse histogram of dst buckets (512 nodes/bucket)
//   bscatter:      LDS-staged radix partition of (src,dst) pairs -> coalesced
//   csr_fill:      one block per bucket: LDS hist+scan+scatter -> exact CSR
//   agg:           one wave per dst node, inline exp(leakyrelu) weights,
//                  single-pass bf16-h weighted aggregate, fused ELU.
// All hot-loop indexing is 32-bit (max index 6.4M) so gathers compile to
// sgpr-base + 32-bit-voffset global loads instead of 64-bit vaddr pairs.

#define NEG_SLOPE 0.2f
#define BSHIFT 9            // 512 nodes per bucket
#define BNODES 512
#define CH 4096             // edges per bscatter block (32 KB LDS staging)

static __device__ __forceinline__ float b2f(unsigned short u) {
    union { unsigned u32; float f; } v; v.u32 = ((unsigned)u) << 16; return v.f;
}
static __device__ __forceinline__ unsigned f2b(float f) {
    union { float f; unsigned u; } v; v.f = f;
    return (v.u + 0x7fffu + ((v.u >> 16) & 1u)) >> 16;   // RNE
}

// ---------------- K1: h = x@W (fp32 VALU) + att_src/att_dst ---------------
__global__ __launch_bounds__(256) void gemm_att_kernel(
    const float* __restrict__ x,       // [N,128]
    const float* __restrict__ W,       // [128,64]
    const float* __restrict__ a_src,   // [4,16]
    const float* __restrict__ a_dst,   // [4,16]
    unsigned short* __restrict__ h_out,// bf16 [N,64]
    float* __restrict__ att_s_o,       // [N,4]
    float* __restrict__ att_d_o,       // [N,4]
    int N)
{
    __shared__ float Wl[128 * 64];     // 32 KB
    int t = threadIdx.x;
    for (int i = t; i < 2048; i += 256)
        ((float4*)Wl)[i] = ((const float4*)W)[i];
    __syncthreads();

    int head = t & 3;
    int g = t >> 2;
    int n0 = blockIdx.x * 256 + g * 4;

    const float4* xr[4];
    #pragma unroll
    for (int j = 0; j < 4; ++j) {
        int nj = min(n0 + j, N - 1);
        xr[j] = (const float4*)(x + nj * 128);
    }

    float acc[4][16];
    #pragma unroll
    for (int j = 0; j < 4; ++j)
        #pragma unroll
        for (int f = 0; f < 16; ++f) acc[j][f] = 0.f;

    const float4* Wl4 = (const float4*)Wl;
    for (int kk = 0; kk < 32; ++kk) {
        float xa[4][4];
        #pragma unroll
        for (int j = 0; j < 4; ++j)
            *(float4*)xa[j] = xr[j][kk];
        #pragma unroll
        for (int k4 = 0; k4 < 4; ++k4) {
            #pragma unroll
            for (int c = 0; c < 4; ++c) {
                float4 wv = Wl4[(kk * 4 + k4) * 16 + head * 4 + c];
                #pragma unroll
                for (int j = 0; j < 4; ++j) {
                    float xk = xa[j][k4];
                    acc[j][c * 4 + 0] = fmaf(xk, wv.x, acc[j][c * 4 + 0]);
                    acc[j][c * 4 + 1] = fmaf(xk, wv.y, acc[j][c * 4 + 1]);
                    acc[j][c * 4 + 2] = fmaf(xk, wv.z, acc[j][c * 4 + 2]);
                    acc[j][c * 4 + 3] = fmaf(xk, wv.w, acc[j][c * 4 + 3]);
                }
            }
        }
    }

    unsigned* h_out_u = (unsigned*)h_out;   // 2 bf16 per uint
    #pragma unroll
    for (int j = 0; j < 4; ++j) {
        int node = n0 + j;
        if (node >= N) break;
        float s = 0.f, d = 0.f;
        #pragma unroll
        for (int f = 0; f < 16; ++f) {
            s = fmaf(acc[j][f], a_src[head * 16 + f], s);
            d = fmaf(acc[j][f], a_dst[head * 16 + f], d);
        }
        att_s_o[node * 4 + head] = s;
        att_d_o[node * 4 + head] = d;

        uint4 pk[2];
        unsigned* pw = (unsigned*)pk;
        #pragma unroll
        for (int p = 0; p < 8; ++p)
            pw[p] = f2b(acc[j][2 * p]) | (f2b(acc[j][2 * p + 1]) << 16);
        uint4* ho = (uint4*)(h_out_u + node * 32 + head * 8);
        ho[0] = pk[0];
        ho[1] = pk[1];
    }
}

// ---------------- K2: coarse bucket count ---------------------------------
__global__ __launch_bounds__(256) void bcount_kernel(
    const int* __restrict__ dst, int* __restrict__ bucketCount, int E)
{
    __shared__ int c[256];
    int t = threadIdx.x;
    c[t] = 0;
    __syncthreads();
    for (int e = blockIdx.x * 256 + t; e < E; e += gridDim.x * 256)
        atomicAdd(&c[dst[e] >> BSHIFT], 1);
    __syncthreads();
    if (c[t]) atomicAdd(&bucketCount[t], c[t]);
}

// ---------------- K3: scan bucket counts; init cursors --------------------
__global__ __launch_bounds__(256) void bscan_kernel(
    const int* __restrict__ bucketCount, int* __restrict__ bucketBase,
    int* __restrict__ bucketCursor, int nb, int E)
{
    __shared__ int sm[256];
    int t = threadIdx.x;
    int v = (t < nb) ? bucketCount[t] : 0;
    sm[t] = v;
    __syncthreads();
    #pragma unroll
    for (int off = 1; off < 256; off <<= 1) {
        int u = (t >= off) ? sm[t - off] : 0;
        __syncthreads();
        sm[t] += u;
        __syncthreads();
    }
    int excl = sm[t] - v;
    if (t <= nb) bucketBase[t] = (t == nb) ? E : excl;
    bucketCursor[t] = (t < nb) ? excl : 0;
}

// ---------------- K4: LDS-staged radix partition of (src,dst) -------------
__global__ __launch_bounds__(256) void bscatter_kernel(
    const int* __restrict__ src, const int* __restrict__ dst,
    int* __restrict__ bucketCursor, int2* __restrict__ pairs, int E)
{
    __shared__ int cnt[256], lo[256], gpos[256], cur[256], sm[256];
    __shared__ int2 staged[CH];        // 32 KB
    int t = threadIdx.x;
    int base = blockIdx.x * CH;
    int nloc = min(CH, E - base);

    cnt[t] = 0;
    __syncthreads();
    for (int i = t; i < nloc; i += 256)
        atomicAdd(&cnt[dst[base + i] >> BSHIFT], 1);
    __syncthreads();

    int v = cnt[t];
    sm[t] = v;
    __syncthreads();
    #pragma unroll
    for (int off = 1; off < 256; off <<= 1) {
        int u = (t >= off) ? sm[t - off] : 0;
        __syncthreads();
        sm[t] += u;
        __syncthreads();
    }
    lo[t] = sm[t] - v;
    cur[t] = lo[t];
    gpos[t] = (v > 0) ? atomicAdd(&bucketCursor[t], v) : 0;
    __syncthreads();

    for (int i = t; i < nloc; i += 256) {
        int d = dst[base + i];
        int s = src[base + i];
        int b = d >> BSHIFT;
        int k = atomicAdd(&cur[b], 1);
        staged[k] = make_int2(s, d);
    }
    __syncthreads();

    for (int i = t; i < nloc; i += 256) {
        int2 p = staged[i];
        int b = p.y >> BSHIFT;
        pairs[gpos[b] + (i - lo[b])] = p;
    }
}

// ---------------- K5: per-bucket CSR fill (one block per bucket) ----------
__global__ __launch_bounds__(512) void csrfill_kernel(
    const int2* __restrict__ pairs, const int* __restrict__ bucketBase,
    int* __restrict__ rowstart, int* __restrict__ elsrc, int N, int E)
{
    __shared__ int hist[512], cur[512], sm[512];
    int b = blockIdx.x, t = threadIdx.x;
    int node_lo = b << BSHIFT;
    int nn = min(BNODES, N - node_lo);
    int ebase = bucketBase[b];
    int ecnt = bucketBase[b + 1] - ebase;

    hist[t] = 0;
    __syncthreads();
    for (int i = t; i < ecnt; i += 512)
        atomicAdd(&hist[pairs[ebase + i].y - node_lo], 1);
    __syncthreads();

    int v = hist[t];
    sm[t] = v;
    __syncthreads();
    #pragma unroll
    for (int off = 1; off < 512; off <<= 1) {
        int u = (t >= off) ? sm[t - off] : 0;
        __syncthreads();
        sm[t] += u;
        __syncthreads();
    }
    int excl = sm[t] - v;
    cur[t] = excl;
    if (t < nn) rowstart[node_lo + t] = ebase + excl;
    if (b == gridDim.x - 1 && t == 0) rowstart[N] = E;
    __syncthreads();

    for (int i = t; i < ecnt; i += 512) {
        int2 p = pairs[ebase + i];
        int k = atomicAdd(&cur[p.y - node_lo], 1);
        elsrc[ebase + k] = p.x;
    }
}

// ---------------- K6: per-node weights + aggregate + ELU (one pass) -------
// One wave per dst node; lane = head*16 + f. All indices 32-bit.
__global__ __launch_bounds__(256) void agg_kernel(
    const int* __restrict__ elsrc,           // [E]
    const int* __restrict__ rowstart,        // [N+1]
    const float* __restrict__ att_s,         // [N,4]
    const float* __restrict__ att_d,         // [N,4]
    const unsigned short* __restrict__ hmat, // bf16 [N,64]
    float* __restrict__ out,                 // [N,64]
    int N)
{
    int node = blockIdx.x * 4 + (threadIdx.x >> 6);
    if (node >= N) return;
    int lane = threadIdx.x & 63;
    int h = lane >> 4;

    int beg = rowstart[node];
    int end = rowstart[node + 1];
    float ad = att_d[(node << 2) | h];

    float l = 0.f, acc = 0.f;
    int i = beg;
    for (; i + 3 < end; i += 4) {
        int s0 = elsrc[i], s1 = elsrc[i+1], s2 = elsrc[i+2], s3 = elsrc[i+3];
        float a0 = att_s[(s0 << 2) | h] + ad;
        float a1 = att_s[(s1 << 2) | h] + ad;
        float a2 = att_s[(s2 << 2) | h] + ad;
        float a3 = att_s[(s3 << 2) | h] + ad;
        float h0 = b2f(hmat[(s0 << 6) | lane]);
        float h1 = b2f(hmat[(s1 << 6) | lane]);
        float h2 = b2f(hmat[(s2 << 6) | lane]);
        float h3 = b2f(hmat[(s3 << 6) | lane]);
        a0 = fmaxf(a0, NEG_SLOPE * a0);
        a1 = fmaxf(a1, NEG_SLOPE * a1);
        a2 = fmaxf(a2, NEG_SLOPE * a2);
        a3 = fmaxf(a3, NEG_SLOPE * a3);
        float w0 = __expf(a0), w1 = __expf(a1), w2 = __expf(a2), w3 = __expf(a3);
        l += (w0 + w1) + (w2 + w3);
        acc = fmaf(w0, h0, acc);
        acc = fmaf(w1, h1, acc);
        acc = fmaf(w2, h2, acc);
        acc = fmaf(w3, h3, acc);
    }
    for (; i < end; ++i) {
        int s0 = elsrc[i];
        float a0 = att_s[(s0 << 2) | h] + ad;
        a0 = fmaxf(a0, NEG_SLOPE * a0);
        float w0 = __expf(a0);
        acc = fmaf(w0, b2f(hmat[(s0 << 6) | lane]), acc);
        l += w0;
    }

    float v = acc / (l + 1e-16f);
    v = (v > 0.f) ? v : (__expf(v) - 1.f);
    out[(node << 6) | lane] = v;
}

extern "C" void kernel_launch(void* const* d_in, const int* in_sizes, int n_in,
                              void* d_out, int out_size, void* d_ws, size_t ws_size,
                              hipStream_t stream) {
    const float* x     = (const float*)d_in[0];
    const int*   ei    = (const int*)d_in[1];
    const float* W     = (const float*)d_in[2];
    const float* a_src = (const float*)d_in[3];
    const float* a_dst = (const float*)d_in[4];

    int N = in_sizes[0] / 128;
    int E = in_sizes[1] / 2;
    const int* src = ei;
    const int* dst = ei + E;
    int nb = (N + BNODES - 1) / BNODES;       // 196 buckets

    char* ws = (char*)d_ws;
    size_t off = 0;
    unsigned short* hmat = (unsigned short*)(ws + off); off += (size_t)N * 64 * 2; // 12.8 MB
    float* att_s = (float*)(ws + off);  off += (size_t)N * 4 * 4;
    float* att_d = (float*)(ws + off);  off += (size_t)N * 4 * 4;
    int* rowstart = (int*)(ws + off);   off += (size_t)(N + 1) * 4;
    int* elsrc    = (int*)(ws + off);   off += (size_t)E * 4;        // 6.4 MB
    int2* pairs   = (int2*)(ws + off);  off += (size_t)E * 8;        // 12.8 MB
    int* bucketBase   = (int*)(ws + off); off += 260 * 4;
    int* bucketCursor = (int*)(ws + off); off += 256 * 4;
    int* bucketCount  = (int*)(ws + off); off += 256 * 4;            // zeroed

    hipMemsetAsync(bucketCount, 0, 256 * 4, stream);

    int blocks1 = (N + 255) / 256;
    gemm_att_kernel<<<blocks1, 256, 0, stream>>>(x, W, a_src, a_dst,
                                                 hmat, att_s, att_d, N);

    bcount_kernel<<<512, 256, 0, stream>>>(dst, bucketCount, E);
    bscan_kernel<<<1, 256, 0, stream>>>(bucketCount, bucketBase, bucketCursor, nb, E);

    int blocksS = (E + CH - 1) / CH;          // 391
    bscatter_kernel<<<blocksS, 256, 0, stream>>>(src, dst, bucketCursor, pairs, E);

    csrfill_kernel<<<nb, 512, 0, stream>>>(pairs, bucketBase, rowstart, elsrc, N, E);

    int blocksA = (N + 3) / 4;
    agg_kernel<<<blocksA, 256, 0, stream>>>(elsrc, rowstart, att_s, att_d,
                                            hmat, (float*)d_out, N);
}

// Round 9
// 267.003 us; speedup vs baseline: 1.0330x; 1.0330x over previous
//
#include <hip/hip_runtime.h>

// GAT layer: N=100000 nodes, E=1.6M edges, IN=128, H=4, F=16 (H*F=64)
// fp32 in/out. Pipeline:
//   gemm_att: h=x@W (register-blocked LDS GEMM, h stored bf16) + att_s/att_d
//   bcount/bscan:  coarse histogram of dst buckets (512 nodes/bucket)
//   bscatter:      LDS-staged radix partition of (src,dst) pairs -> coalesced
//   csr_fill:      one block per bucket: LDS hist+scan+scatter -> exact CSR
//   agg:           one wave per dst node, 4 edges per iteration:
//                  lane = eslot(0..3)*16 + q(0..15); 16-lane group = 1 edge,
//                  lane q holds features 4q..4q+3 (uint2 = 4 bf16). 1 VMEM
//                  per {elsrc, att_s, hmat} per 4 edges instead of per edge.
//                  Inline exp(leakyrelu) weights (no max-shift: |e|<~25,
//                  fp32-safe; softmax shift-invariant), shfl-reduce, ELU.

#define NEG_SLOPE 0.2f
#define BSHIFT 9            // 512 nodes per bucket
#define BNODES 512
#define CH 4096             // edges per bscatter block (32 KB LDS staging)

static __device__ __forceinline__ float b2f(unsigned short u) {
    union { unsigned u32; float f; } v; v.u32 = ((unsigned)u) << 16; return v.f;
}
static __device__ __forceinline__ unsigned f2b(float f) {
    union { float f; unsigned u; } v; v.f = f;
    return (v.u + 0x7fffu + ((v.u >> 16) & 1u)) >> 16;   // RNE
}
static __device__ __forceinline__ float u2f(unsigned u) {
    union { unsigned u32; float f; } v; v.u32 = u; return v.f;
}

// ---------------- K1: h = x@W (fp32 VALU) + att_src/att_dst ---------------
__global__ __launch_bounds__(256) void gemm_att_kernel(
    const float* __restrict__ x,       // [N,128]
    const float* __restrict__ W,       // [128,64]
    const float* __restrict__ a_src,   // [4,16]
    const float* __restrict__ a_dst,   // [4,16]
    unsigned short* __restrict__ h_out,// bf16 [N,64]
    float* __restrict__ att_s_o,       // [N,4]
    float* __restrict__ att_d_o,       // [N,4]
    int N)
{
    __shared__ float Wl[128 * 64];     // 32 KB
    int t = threadIdx.x;
    for (int i = t; i < 2048; i += 256)
        ((float4*)Wl)[i] = ((const float4*)W)[i];
    __syncthreads();

    int head = t & 3;
    int g = t >> 2;
    int n0 = blockIdx.x * 256 + g * 4;

    const float4* xr[4];
    #pragma unroll
    for (int j = 0; j < 4; ++j) {
        int nj = min(n0 + j, N - 1);
        xr[j] = (const float4*)(x + nj * 128);
    }

    float acc[4][16];
    #pragma unroll
    for (int j = 0; j < 4; ++j)
        #pragma unroll
        for (int f = 0; f < 16; ++f) acc[j][f] = 0.f;

    const float4* Wl4 = (const float4*)Wl;
    for (int kk = 0; kk < 32; ++kk) {
        float xa[4][4];
        #pragma unroll
        for (int j = 0; j < 4; ++j)
            *(float4*)xa[j] = xr[j][kk];
        #pragma unroll
        for (int k4 = 0; k4 < 4; ++k4) {
            #pragma unroll
            for (int c = 0; c < 4; ++c) {
                float4 wv = Wl4[(kk * 4 + k4) * 16 + head * 4 + c];
                #pragma unroll
                for (int j = 0; j < 4; ++j) {
                    float xk = xa[j][k4];
                    acc[j][c * 4 + 0] = fmaf(xk, wv.x, acc[j][c * 4 + 0]);
                    acc[j][c * 4 + 1] = fmaf(xk, wv.y, acc[j][c * 4 + 1]);
                    acc[j][c * 4 + 2] = fmaf(xk, wv.z, acc[j][c * 4 + 2]);
                    acc[j][c * 4 + 3] = fmaf(xk, wv.w, acc[j][c * 4 + 3]);
                }
            }
        }
    }

    unsigned* h_out_u = (unsigned*)h_out;   // 2 bf16 per uint
    #pragma unroll
    for (int j = 0; j < 4; ++j) {
        int node = n0 + j;
        if (node >= N) break;
        float s = 0.f, d = 0.f;
        #pragma unroll
        for (int f = 0; f < 16; ++f) {
            s = fmaf(acc[j][f], a_src[head * 16 + f], s);
            d = fmaf(acc[j][f], a_dst[head * 16 + f], d);
        }
        att_s_o[node * 4 + head] = s;
        att_d_o[node * 4 + head] = d;

        uint4 pk[2];
        unsigned* pw = (unsigned*)pk;
        #pragma unroll
        for (int p = 0; p < 8; ++p)
            pw[p] = f2b(acc[j][2 * p]) | (f2b(acc[j][2 * p + 1]) << 16);
        uint4* ho = (uint4*)(h_out_u + node * 32 + head * 8);
        ho[0] = pk[0];
        ho[1] = pk[1];
    }
}

// ---------------- K2: coarse bucket count ---------------------------------
__global__ __launch_bounds__(256) void bcount_kernel(
    const int* __restrict__ dst, int* __restrict__ bucketCount, int E)
{
    __shared__ int c[256];
    int t = threadIdx.x;
    c[t] = 0;
    __syncthreads();
    for (int e = blockIdx.x * 256 + t; e < E; e += gridDim.x * 256)
        atomicAdd(&c[dst[e] >> BSHIFT], 1);
    __syncthreads();
    if (c[t]) atomicAdd(&bucketCount[t], c[t]);
}

// ---------------- K3: scan bucket counts; init cursors --------------------
__global__ __launch_bounds__(256) void bscan_kernel(
    const int* __restrict__ bucketCount, int* __restrict__ bucketBase,
    int* __restrict__ bucketCursor, int nb, int E)
{
    __shared__ int sm[256];
    int t = threadIdx.x;
    int v = (t < nb) ? bucketCount[t] : 0;
    sm[t] = v;
    __syncthreads();
    #pragma unroll
    for (int off = 1; off < 256; off <<= 1) {
        int u = (t >= off) ? sm[t - off] : 0;
        __syncthreads();
        sm[t] += u;
        __syncthreads();
    }
    int excl = sm[t] - v;
    if (t <= nb) bucketBase[t] = (t == nb) ? E : excl;
    bucketCursor[t] = (t < nb) ? excl : 0;
}

// ---------------- K4: LDS-staged radix partition of (src,dst) -------------
__global__ __launch_bounds__(256) void bscatter_kernel(
    const int* __restrict__ src, const int* __restrict__ dst,
    int* __restrict__ bucketCursor, int2* __restrict__ pairs, int E)
{
    __shared__ int cnt[256], lo[256], gpos[256], cur[256], sm[256];
    __shared__ int2 staged[CH];        // 32 KB
    int t = threadIdx.x;
    int base = blockIdx.x * CH;
    int nloc = min(CH, E - base);

    cnt[t] = 0;
    __syncthreads();
    for (int i = t; i < nloc; i += 256)
        atomicAdd(&cnt[dst[base + i] >> BSHIFT], 1);
    __syncthreads();

    int v = cnt[t];
    sm[t] = v;
    __syncthreads();
    #pragma unroll
    for (int off = 1; off < 256; off <<= 1) {
        int u = (t >= off) ? sm[t - off] : 0;
        __syncthreads();
        sm[t] += u;
        __syncthreads();
    }
    lo[t] = sm[t] - v;
    cur[t] = lo[t];
    gpos[t] = (v > 0) ? atomicAdd(&bucketCursor[t], v) : 0;
    __syncthreads();

    for (int i = t; i < nloc; i += 256) {
        int d = dst[base + i];
        int s = src[base + i];
        int b = d >> BSHIFT;
        int k = atomicAdd(&cur[b], 1);
        staged[k] = make_int2(s, d);
    }
    __syncthreads();

    for (int i = t; i < nloc; i += 256) {
        int2 p = staged[i];
        int b = p.y >> BSHIFT;
        pairs[gpos[b] + (i - lo[b])] = p;
    }
}

// ---------------- K5: per-bucket CSR fill (one block per bucket) ----------
__global__ __launch_bounds__(512) void csrfill_kernel(
    const int2* __restrict__ pairs, const int* __restrict__ bucketBase,
    int* __restrict__ rowstart, int* __restrict__ elsrc, int N, int E)
{
    __shared__ int hist[512], cur[512], sm[512];
    int b = blockIdx.x, t = threadIdx.x;
    int node_lo = b << BSHIFT;
    int nn = min(BNODES, N - node_lo);
    int ebase = bucketBase[b];
    int ecnt = bucketBase[b + 1] - ebase;

    hist[t] = 0;
    __syncthreads();
    for (int i = t; i < ecnt; i += 512)
        atomicAdd(&hist[pairs[ebase + i].y - node_lo], 1);
    __syncthreads();

    int v = hist[t];
    sm[t] = v;
    __syncthreads();
    #pragma unroll
    for (int off = 1; off < 512; off <<= 1) {
        int u = (t >= off) ? sm[t - off] : 0;
        __syncthreads();
        sm[t] += u;
        __syncthreads();
    }
    int excl = sm[t] - v;
    cur[t] = excl;
    if (t < nn) rowstart[node_lo + t] = ebase + excl;
    if (b == gridDim.x - 1 && t == 0) rowstart[N] = E;
    __syncthreads();

    for (int i = t; i < ecnt; i += 512) {
        int2 p = pairs[ebase + i];
        int k = atomicAdd(&cur[p.y - node_lo], 1);
        elsrc[ebase + k] = p.x;
    }
}

// ---------------- K6: per-node aggregate, 4 edges/iteration ---------------
// One wave per dst node. lane = eslot*16 + q; q indexes feature quad 4q..4q+3,
// head = q>>2. Each 16-lane group handles a different edge of this node.
__global__ __launch_bounds__(256) void agg_kernel(
    const int* __restrict__ elsrc,           // [E]
    const int* __restrict__ rowstart,        // [N+1]
    const float* __restrict__ att_s,         // [N,4]
    const float* __restrict__ att_d,         // [N,4]
    const unsigned short* __restrict__ hmat, // bf16 [N,64]
    float* __restrict__ out,                 // [N,64]
    int N)
{
    int node = blockIdx.x * 4 + (threadIdx.x >> 6);
    if (node >= N) return;
    int lane = threadIdx.x & 63;
    int q = lane & 15;       // feature quad
    int eslot = lane >> 4;   // 0..3
    int h = q >> 2;          // head

    int beg = rowstart[node];
    int deg = rowstart[node + 1] - beg;
    float ad = att_d[(node << 2) | h];

    float a0 = 0.f, a1 = 0.f, a2 = 0.f, a3 = 0.f, l = 0.f;

    for (int base = 0; base < deg; base += 4) {
        int e = base + eslot;
        int idx = beg + min(e, deg - 1);
        int s = elsrc[idx];
        float av = att_s[(s << 2) | h] + ad;
        av = fmaxf(av, NEG_SLOPE * av);
        float w = (e < deg) ? __expf(av) : 0.f;
        l += w;
        uint2 hp = *(const uint2*)(hmat + (s << 6) + (q << 2));
        a0 = fmaf(w, u2f(hp.x << 16), a0);
        a1 = fmaf(w, u2f(hp.x & 0xffff0000u), a1);
        a2 = fmaf(w, u2f(hp.y << 16), a2);
        a3 = fmaf(w, u2f(hp.y & 0xffff0000u), a3);
    }

    // reduce across the 4 edge slots (lane bits 4 and 5)
    #pragma unroll
    for (int m = 16; m <= 32; m <<= 1) {
        a0 += __shfl_xor(a0, m, 64);
        a1 += __shfl_xor(a1, m, 64);
        a2 += __shfl_xor(a2, m, 64);
        a3 += __shfl_xor(a3, m, 64);
        l  += __shfl_xor(l,  m, 64);
    }

    if (eslot == 0) {
        float rl = 1.0f / (l + 1e-16f);
        float4 v;
        v.x = a0 * rl; v.x = (v.x > 0.f) ? v.x : (__expf(v.x) - 1.f);
        v.y = a1 * rl; v.y = (v.y > 0.f) ? v.y : (__expf(v.y) - 1.f);
        v.z = a2 * rl; v.z = (v.z > 0.f) ? v.z : (__expf(v.z) - 1.f);
        v.w = a3 * rl; v.w = (v.w > 0.f) ? v.w : (__expf(v.w) - 1.f);
        *(float4*)(out + (node << 6) + (q << 2)) = v;
    }
}

extern "C" void kernel_launch(void* const* d_in, const int* in_sizes, int n_in,
                              void* d_out, int out_size, void* d_ws, size_t ws_size,
                              hipStream_t stream) {
    const float* x     = (const float*)d_in[0];
    const int*   ei    = (const int*)d_in[1];
    const float* W     = (const float*)d_in[2];
    const float* a_src = (const float*)d_in[3];
    const float* a_dst = (const float*)d_in[4];

    int N = in_sizes[0] / 128;
    int E = in_sizes[1] / 2;
    const int* src = ei;
    const int* dst = ei + E;
    int nb = (N + BNODES - 1) / BNODES;       // 196 buckets

    char* ws = (char*)d_ws;
    size_t off = 0;
    unsigned short* hmat = (unsigned short*)(ws + off); off += (size_t)N * 64 * 2; // 12.8 MB
    float* att_s = (float*)(ws + off);  off += (size_t)N * 4 * 4;
    float* att_d = (float*)(ws + off);  off += (size_t)N * 4 * 4;
    int* rowstart = (int*)(ws + off);   off += (size_t)(N + 1) * 4;
    int* elsrc    = (int*)(ws + off);   off += (size_t)E * 4;        // 6.4 MB
    int2* pairs   = (int2*)(ws + off);  off += (size_t)E * 8;        // 12.8 MB
    int* bucketBase   = (int*)(ws + off); off += 260 * 4;
    int* bucketCursor = (int*)(ws + off); off += 256 * 4;
    int* bucketCount  = (int*)(ws + off); off += 256 * 4;            // zeroed

    hipMemsetAsync(bucketCount, 0, 256 * 4, stream);

    int blocks1 = (N + 255) / 256;
    gemm_att_kernel<<<blocks1, 256, 0, stream>>>(x, W, a_src, a_dst,
                                                 hmat, att_s, att_d, N);

    bcount_kernel<<<512, 256, 0, stream>>>(dst, bucketCount, E);
    bscan_kernel<<<1, 256, 0, stream>>>(bucketCount, bucketBase, bucketCursor, nb, E);

    int blocksS = (E + CH - 1) / CH;          // 391
    bscatter_kernel<<<blocksS, 256, 0, stream>>>(src, dst, bucketCursor, pairs, E);

    csrfill_kernel<<<nb, 512, 0, stream>>>(pairs, bucketBase, rowstart, elsrc, N, E);

    int blocksA = (N + 3) / 4;
    agg_kernel<<<blocksA, 256, 0, stream>>>(elsrc, rowstart, att_s, att_d,
                                            hmat, (float*)d_out, N);
}

// Round 10
// 237.750 us; speedup vs baseline: 1.1601x; 1.1230x over previous
//
#include <hip/hip_runtime.h>

// GAT layer: N=100000 nodes, E=1.6M edges, IN=128, H=4, F=16 (H*F=64)
// fp32 in/out. Pipeline:
//   gemm_att: h=x@W via bf16 MFMA (W swizzled to B-frag layout in LDS),
//             h stored bf16, att_s/att_d fp32 epilogue
//   bcount/bscan:  coarse histogram of dst buckets (512 nodes/bucket)
//   bscatter:      LDS-staged radix partition -> packed (src<<9|dstloc) ints,
//                  CH=2048 for ~3 blocks/CU occupancy
//   csr_fill:      one 1024-thread block per bucket: LDS hist+scan+scatter
//   agg:           one wave per dst node, 8 edges/iter: lane = eslot(3b)*8+q;
//                  8-lane group = 1 edge, lane q holds features 8q..8q+7
//                  (uint4 = 8 bf16). Inline exp(leakyrelu) (no max-shift:
//                  |e|<~25 fp32-safe; softmax shift-invariant), shfl-reduce,
//                  fused ELU.

#define NEG_SLOPE 0.2f
#define BSHIFT 9            // 512 nodes per bucket
#define BNODES 512
#define CH 2048             // edges per bscatter block (16 KB LDS staging)

typedef __bf16 bf16x8 __attribute__((ext_vector_type(8)));
typedef float  f32x4  __attribute__((ext_vector_type(4)));

static __device__ __forceinline__ unsigned f2b(float f) {
    union { float f; unsigned u; } v; v.f = f;
    return (v.u + 0x7fffu + ((v.u >> 16) & 1u)) >> 16;   // RNE
}
static __device__ __forceinline__ float u2f(unsigned u) {
    union { unsigned u32; float f; } v; v.u32 = u; return v.f;
}

// ---------------- K1: h = x@W (bf16 MFMA) + att_src/att_dst ---------------
// Block = 256 = 4 waves; one wave per 16 nodes. W -> LDS B-fragments.
// Fragment layouts (m89/m91-verified): A[m=lane&15][k=quad*8+j],
// B[k=quad*8+j][n=lane&15], D col=lane&15, row=quad*4+reg.
__global__ __launch_bounds__(256) void gemm_att_kernel(
    const float* __restrict__ x,       // [N,128]
    const float* __restrict__ W,       // [128,64]
    const float* __restrict__ a_src,   // [4,16]
    const float* __restrict__ a_dst,   // [4,16]
    unsigned short* __restrict__ h_out,// bf16 [N,64]
    float* __restrict__ att_s_o,       // [N,4]
    float* __restrict__ att_d_o,       // [N,4]
    int N)
{
    __shared__ bf16x8 Wswz[16][64];    // [cb*4+tt][lane], 16 KB
    int t = threadIdx.x;
    for (int i = t; i < 8192; i += 256) {            // W[k][n], coalesced read
        int k = i >> 6, n = i & 63;
        __bf16* dp = (__bf16*)&Wswz[((n >> 4) << 2) | (k >> 5)]
                                   [(((k >> 3) & 3) << 4) | (n & 15)];
        dp[k & 7] = (__bf16)W[i];
    }
    __syncthreads();

    int wave = t >> 6;
    int lane = t & 63;
    int col = lane & 15, quad = lane >> 4;
    int node_base = (blockIdx.x * 4 + wave) * 16;
    int arow = min(node_base + col, N - 1);
    const float* xp = x + arow * 128;

    bf16x8 af[4];
    #pragma unroll
    for (int tt = 0; tt < 4; ++tt) {
        float4 xa = *(const float4*)(xp + tt * 32 + quad * 8);
        float4 xb = *(const float4*)(xp + tt * 32 + quad * 8 + 4);
        bf16x8 f;
        f[0] = (__bf16)xa.x; f[1] = (__bf16)xa.y;
        f[2] = (__bf16)xa.z; f[3] = (__bf16)xa.w;
        f[4] = (__bf16)xb.x; f[5] = (__bf16)xb.y;
        f[6] = (__bf16)xb.z; f[7] = (__bf16)xb.w;
        af[tt] = f;
    }

    f32x4 acc[4];
    #pragma unroll
    for (int cb = 0; cb < 4; ++cb) {
        acc[cb] = (f32x4){0.f, 0.f, 0.f, 0.f};
        #pragma unroll
        for (int tt = 0; tt < 4; ++tt)
            acc[cb] = __builtin_amdgcn_mfma_f32_16x16x32_bf16(
                af[tt], Wswz[(cb << 2) | tt][lane], acc[cb], 0, 0, 0);
    }

    #pragma unroll
    for (int cb = 0; cb < 4; ++cb) {
        float ws_ = a_src[cb * 16 + col];
        float wd_ = a_dst[cb * 16 + col];
        #pragma unroll
        for (int r = 0; r < 4; ++r) {
            float v = acc[cb][r];
            int node = node_base + quad * 4 + r;
            float s = v * ws_, d = v * wd_;
            #pragma unroll
            for (int m = 1; m < 16; m <<= 1) {
                s += __shfl_xor(s, m, 64);
                d += __shfl_xor(d, m, 64);
            }
            if (node < N) {
                h_out[node * 64 + cb * 16 + col] = (unsigned short)f2b(v);
                if (col == 0) {
                    att_s_o[(node << 2) | cb] = s;
                    att_d_o[(node << 2) | cb] = d;
                }
            }
        }
    }
}

// ---------------- K2: coarse bucket count ---------------------------------
__global__ __launch_bounds__(256) void bcount_kernel(
    const int* __restrict__ dst, int* __restrict__ bucketCount, int E)
{
    __shared__ int c[256];
    int t = threadIdx.x;
    c[t] = 0;
    __syncthreads();
    for (int e = blockIdx.x * 256 + t; e < E; e += gridDim.x * 256)
        atomicAdd(&c[dst[e] >> BSHIFT], 1);
    __syncthreads();
    if (c[t]) atomicAdd(&bucketCount[t], c[t]);
}

// ---------------- K3: scan bucket counts; init cursors --------------------
__global__ __launch_bounds__(256) void bscan_kernel(
    const int* __restrict__ bucketCount, int* __restrict__ bucketBase,
    int* __restrict__ bucketCursor, int nb, int E)
{
    __shared__ int sm[256];
    int t = threadIdx.x;
    int v = (t < nb) ? bucketCount[t] : 0;
    sm[t] = v;
    __syncthreads();
    #pragma unroll
    for (int off = 1; off < 256; off <<= 1) {
        int u = (t >= off) ? sm[t - off] : 0;
        __syncthreads();
        sm[t] += u;
        __syncthreads();
    }
    int excl = sm[t] - v;
    if (t <= nb) bucketBase[t] = (t == nb) ? E : excl;
    bucketCursor[t] = (t < nb) ? excl : 0;
}

// ---------------- K4: LDS-staged radix partition -> packed ints -----------
__global__ __launch_bounds__(256) void bscatter_kernel(
    const int* __restrict__ src, const int* __restrict__ dst,
    int* __restrict__ bucketCursor, int* __restrict__ pairs, int E)
{
    __shared__ int cnt[256], lo[256], gpos[256], cur[256], sm[256];
    __shared__ int2 staged[CH];        // .x = packed (s<<9|dloc), .y = bucket
    int t = threadIdx.x;
    int base = blockIdx.x * CH;
    int nloc = min(CH, E - base);

    cnt[t] = 0;
    __syncthreads();
    for (int i = t; i < nloc; i += 256)
        atomicAdd(&cnt[dst[base + i] >> BSHIFT], 1);
    __syncthreads();

    int v = cnt[t];
    sm[t] = v;
    __syncthreads();
    #pragma unroll
    for (int off = 1; off < 256; off <<= 1) {
        int u = (t >= off) ? sm[t - off] : 0;
        __syncthreads();
        sm[t] += u;
        __syncthreads();
    }
    lo[t] = sm[t] - v;
    cur[t] = lo[t];
    gpos[t] = (v > 0) ? atomicAdd(&bucketCursor[t], v) : 0;
    __syncthreads();

    for (int i = t; i < nloc; i += 256) {
        int d = dst[base + i];
        int s = src[base + i];
        int b = d >> BSHIFT;
        int k = atomicAdd(&cur[b], 1);
        staged[k] = make_int2((s << BSHIFT) | (d & (BNODES - 1)), b);
    }
    __syncthreads();

    for (int i = t; i < nloc; i += 256) {
        int2 p = staged[i];
        pairs[gpos[p.y] + (i - lo[p.y])] = p.x;
    }
}

// ---------------- K5: per-bucket CSR fill (1024 threads/bucket) -----------
__global__ __launch_bounds__(1024) void csrfill_kernel(
    const int* __restrict__ pairs, const int* __restrict__ bucketBase,
    int* __restrict__ rowstart, int* __restrict__ elsrc, int N, int E)
{
    __shared__ int hist[512], cur[512], sm[512];
    int b = blockIdx.x, t = threadIdx.x;
    int node_lo = b << BSHIFT;
    int nn = min(BNODES, N - node_lo);
    int ebase = bucketBase[b];
    int ecnt = bucketBase[b + 1] - ebase;

    if (t < 512) hist[t] = 0;
    __syncthreads();
    for (int i = t; i < ecnt; i += 1024)
        atomicAdd(&hist[pairs[ebase + i] & (BNODES - 1)], 1);
    __syncthreads();

    int v = (t < 512) ? hist[t] : 0;
    if (t < 512) sm[t] = v;
    __syncthreads();
    #pragma unroll
    for (int off = 1; off < 512; off <<= 1) {
        int u = (t >= off && t < 512) ? sm[t - off] : 0;
        __syncthreads();
        if (t < 512) sm[t] += u;
        __syncthreads();
    }
    if (t < 512) {
        int excl = sm[t] - v;
        cur[t] = excl;
        if (t < nn) rowstart[node_lo + t] = ebase + excl;
    }
    if (b == gridDim.x - 1 && t == 0) rowstart[N] = E;
    __syncthreads();

    for (int i = t; i < ecnt; i += 1024) {
        int p = pairs[ebase + i];
        int k = atomicAdd(&cur[p & (BNODES - 1)], 1);
        elsrc[ebase + k] = p >> BSHIFT;
    }
}

// ---------------- K6: per-node aggregate, 8 edges/iteration ---------------
// One wave per dst node. lane = eslot*8 + q; lane q holds features 8q..8q+7
// (uint4 = 8 bf16), head = q>>1. 8-lane group = 1 edge.
__global__ __launch_bounds__(256) void agg_kernel(
    const int* __restrict__ elsrc,           // [E]
    const int* __restrict__ rowstart,        // [N+1]
    const float* __restrict__ att_s,         // [N,4]
    const float* __restrict__ att_d,         // [N,4]
    const unsigned short* __restrict__ hmat, // bf16 [N,64]
    float* __restrict__ out,                 // [N,64]
    int N)
{
    int node = blockIdx.x * 4 + (threadIdx.x >> 6);
    if (node >= N) return;
    int lane = threadIdx.x & 63;
    int q = lane & 7;        // feature octet
    int eslot = lane >> 3;   // 0..7
    int h = q >> 1;          // head

    int beg = rowstart[node];
    int deg = rowstart[node + 1] - beg;
    float ad = att_d[(node << 2) | h];

    float a0 = 0.f, a1 = 0.f, a2 = 0.f, a3 = 0.f;
    float a4 = 0.f, a5 = 0.f, a6 = 0.f, a7 = 0.f, l = 0.f;

    for (int base = 0; base < deg; base += 8) {
        int e = base + eslot;
        int idx = beg + min(e, deg - 1);
        int s = elsrc[idx];
        float av = att_s[(s << 2) | h] + ad;
        av = fmaxf(av, NEG_SLOPE * av);
        float w = (e < deg) ? __expf(av) : 0.f;
        l += w;
        uint4 hp = *(const uint4*)(hmat + (s << 6) + (q << 3));
        a0 = fmaf(w, u2f(hp.x << 16), a0);
        a1 = fmaf(w, u2f(hp.x & 0xffff0000u), a1);
        a2 = fmaf(w, u2f(hp.y << 16), a2);
        a3 = fmaf(w, u2f(hp.y & 0xffff0000u), a3);
        a4 = fmaf(w, u2f(hp.z << 16), a4);
        a5 = fmaf(w, u2f(hp.z & 0xffff0000u), a5);
        a6 = fmaf(w, u2f(hp.w << 16), a6);
        a7 = fmaf(w, u2f(hp.w & 0xffff0000u), a7);
    }

    // reduce across the 8 edge slots (lane bits 3,4,5)
    #pragma unroll
    for (int m = 8; m <= 32; m <<= 1) {
        a0 += __shfl_xor(a0, m, 64);
        a1 += __shfl_xor(a1, m, 64);
        a2 += __shfl_xor(a2, m, 64);
        a3 += __shfl_xor(a3, m, 64);
        a4 += __shfl_xor(a4, m, 64);
        a5 += __shfl_xor(a5, m, 64);
        a6 += __shfl_xor(a6, m, 64);
        a7 += __shfl_xor(a7, m, 64);
        l  += __shfl_xor(l,  m, 64);
    }

    if (eslot == 0) {
        float rl = 1.0f / (l + 1e-16f);
        float4 v0, v1;
        v0.x = a0 * rl; v0.x = (v0.x > 0.f) ? v0.x : (__expf(v0.x) - 1.f);
        v0.y = a1 * rl; v0.y = (v0.y > 0.f) ? v0.y : (__expf(v0.y) - 1.f);
        v0.z = a2 * rl; v0.z = (v0.z > 0.f) ? v0.z : (__expf(v0.z) - 1.f);
        v0.w = a3 * rl; v0.w = (v0.w > 0.f) ? v0.w : (__expf(v0.w) - 1.f);
        v1.x = a4 * rl; v1.x = (v1.x > 0.f) ? v1.x : (__expf(v1.x) - 1.f);
        v1.y = a5 * rl; v1.y = (v1.y > 0.f) ? v1.y : (__expf(v1.y) - 1.f);
        v1.z = a6 * rl; v1.z = (v1.z > 0.f) ? v1.z : (__expf(v1.z) - 1.f);
        v1.w = a7 * rl; v1.w = (v1.w > 0.f) ? v1.w : (__expf(v1.w) - 1.f);
        float* op = out + (node << 6) + (q << 3);
        *(float4*)op = v0;
        *(float4*)(op + 4) = v1;
    }
}

extern "C" void kernel_launch(void* const* d_in, const int* in_sizes, int n_in,
                              void* d_out, int out_size, void* d_ws, size_t ws_size,
                              hipStream_t stream) {
    const float* x     = (const float*)d_in[0];
    const int*   ei    = (const int*)d_in[1];
    const float* W     = (const float*)d_in[2];
    const float* a_src = (const float*)d_in[3];
    const float* a_dst = (const float*)d_in[4];

    int N = in_sizes[0] / 128;
    int E = in_sizes[1] / 2;
    const int* src = ei;
    const int* dst = ei + E;
    int nb = (N + BNODES - 1) / BNODES;       // 196 buckets

    char* ws = (char*)d_ws;
    size_t off = 0;
    unsigned short* hmat = (unsigned short*)(ws + off); off += (size_t)N * 64 * 2; // 12.8 MB
    float* att_s = (float*)(ws + off);  off += (size_t)N * 4 * 4;
    float* att_d = (float*)(ws + off);  off += (size_t)N * 4 * 4;
    int* rowstart = (int*)(ws + off);   off += (size_t)(N + 1) * 4;
    int* elsrc    = (int*)(ws + off);   off += (size_t)E * 4;        // 6.4 MB
    int* pairs    = (int*)(ws + off);   off += (size_t)E * 4;        // 6.4 MB
    int* bucketBase   = (int*)(ws + off); off += 260 * 4;
    int* bucketCursor = (int*)(ws + off); off += 256 * 4;
    int* bucketCount  = (int*)(ws + off); off += 256 * 4;            // zeroed

    hipMemsetAsync(bucketCount, 0, 256 * 4, stream);

    int blocks1 = (N + 63) / 64;              // 1563, one wave per 16 nodes
    gemm_att_kernel<<<blocks1, 256, 0, stream>>>(x, W, a_src, a_dst,
                                                 hmat, att_s, att_d, N);

    bcount_kernel<<<512, 256, 0, stream>>>(dst, bucketCount, E);
    bscan_kernel<<<1, 256, 0, stream>>>(bucketCount, bucketBase, bucketCursor, nb, E);

    int blocksS = (E + CH - 1) / CH;          // 782
    bscatter_kernel<<<blocksS, 256, 0, stream>>>(src, dst, bucketCursor, pairs, E);

    csrfill_kernel<<<nb, 1024, 0, stream>>>(pairs, bucketBase, rowstart, elsrc, N, E);

    int blocksA = (N + 3) / 4;
    agg_kernel<<<blocksA, 256, 0, stream>>>(elsrc, rowstart, att_s, att_d,
                                            hmat, (float*)d_out, N);
}

// Round 11
// 224.204 us; speedup vs baseline: 1.2302x; 1.0604x over previous
//
#include <hip/hip_runtime.h>

// GAT layer: N=100000 nodes, E=1.6M edges, IN=128, H=4, F=16 (H*F=64)
// fp32 in/out. 5 dispatches:
//   memset:    bucketCount+bucketCursor = 0
//   gemm_att (+fused bcount tail blocks):
//              h=x@W via bf16 MFMA; att = x@(W@a) folded into 8 extra
//              B-columns (one extra MFMA chain -> att lands in D cols 0..7,
//              no shuffle reduction). h stored bf16.
//   bscatter:  LDS-staged radix partition -> packed (src<<9|dstloc) ints;
//              bucket bases computed by local LDS scan of bucketCount
//              (bucketCursor holds bucket-relative offsets; no bscan kernel)
//   csr_fill:  one 1024-thread block per bucket: local base scan + LDS
//              hist/scan/scatter -> exact CSR (elsrc + rowstart)
//   agg:       one wave per dst node, 8 edges/iter: lane = eslot(3b)*8+q;
//              8-lane group = 1 edge, lane q holds features 8q..8q+7 (uint4 =
//              8 bf16). Inline exp(leakyrelu) (no max-shift: |e|<~25
//              fp32-safe; softmax shift-invariant), shfl-reduce, fused ELU.

#define NEG_SLOPE 0.2f
#define BSHIFT 9            // 512 nodes per bucket
#define BNODES 512
#define CH 2048             // edges per bscatter block (16 KB LDS staging)
#define BCB 512             // bcount blocks fused into gemm grid

typedef __bf16 bf16x8 __attribute__((ext_vector_type(8)));
typedef float  f32x4  __attribute__((ext_vector_type(4)));

static __device__ __forceinline__ unsigned f2b(float f) {
    union { float f; unsigned u; } v; v.f = f;
    return (v.u + 0x7fffu + ((v.u >> 16) & 1u)) >> 16;   // RNE
}
static __device__ __forceinline__ float u2f(unsigned u) {
    union { unsigned u32; float f; } v; v.u32 = u; return v.f;
}

// ---------------- K1: h = x@W (bf16 MFMA) + att MFMA + fused bcount -------
// gemm blocks: 256 thr = 4 waves, one wave per 16 nodes. W -> LDS B-frags.
// Layouts (m89/m91-verified): A[m=lane&15][k=quad*8+j],
// B[k=quad*8+j][n=lane&15], D col=lane&15, row=quad*4+reg.
// Extra B entry rows 16..19 hold [ws(4 heads)|wd(4 heads)|0...] where
// ws[k][hd] = sum_f W[k][hd*16+f]*a_src[hd][f]  (att = x @ (W@a)).
__global__ __launch_bounds__(256) void gemm_att_kernel(
    const float* __restrict__ x,       // [N,128]
    const float* __restrict__ W,       // [128,64]
    const float* __restrict__ a_src,   // [4,16]
    const float* __restrict__ a_dst,   // [4,16]
    unsigned short* __restrict__ h_out,// bf16 [N,64]
    float* __restrict__ att_s_o,       // [N,4]
    float* __restrict__ att_d_o,       // [N,4]
    const int* __restrict__ dst,       // [E] (bcount part)
    int* __restrict__ bucketCount,
    int N, int E, int gemmBlocks)
{
    __shared__ bf16x8 Wswz[20][64];    // 20 KB
    __shared__ int c[256];
    int t = threadIdx.x;

    if (blockIdx.x >= gemmBlocks) {    // ---- bcount path ----
        int bid = blockIdx.x - gemmBlocks;
        c[t] = 0;
        __syncthreads();
        for (int e = bid * 256 + t; e < E; e += BCB * 256)
            atomicAdd(&c[dst[e] >> BSHIFT], 1);
        __syncthreads();
        if (c[t]) atomicAdd(&bucketCount[t], c[t]);
        return;
    }

    // ---- W swizzle ----
    for (int i = t; i < 8192; i += 256) {            // W[k][n], coalesced
        int k = i >> 6, n = i & 63;
        __bf16* dp = (__bf16*)&Wswz[((n >> 4) << 2) | (k >> 5)]
                                   [(((k >> 3) & 3) << 4) | (n & 15)];
        dp[k & 7] = (__bf16)W[i];
    }
    // ---- ws/wd fold: entry 16+tt, cols 0..7 = [ws|wd], cols 8..15 = 0 ----
    for (int i = t; i < 1024; i += 256) {            // k(128) x c7(8)
        int k = i >> 3, c7 = i & 7;
        int hd = c7 & 3;
        const float* aa = (c7 < 4) ? a_src : a_dst;
        float sum = 0.f;
        #pragma unroll
        for (int f = 0; f < 16; ++f)
            sum = fmaf(W[k * 64 + hd * 16 + f], aa[hd * 16 + f], sum);
        __bf16* dp = (__bf16*)&Wswz[16 + (k >> 5)][(((k >> 3) & 3) << 4) | c7];
        dp[k & 7] = (__bf16)sum;
        __bf16* dz = (__bf16*)&Wswz[16 + (k >> 5)][(((k >> 3) & 3) << 4) | (8 + c7)];
        dz[k & 7] = (__bf16)0.f;
    }
    __syncthreads();

    int wave = t >> 6;
    int lane = t & 63;
    int col = lane & 15, quad = lane >> 4;
    int node_base = (blockIdx.x * 4 + wave) * 16;
    int arow = min(node_base + col, N - 1);
    const float* xp = x + arow * 128;

    bf16x8 af[4];
    #pragma unroll
    for (int tt = 0; tt < 4; ++tt) {
        float4 xa = *(const float4*)(xp + tt * 32 + quad * 8);
        float4 xb = *(const float4*)(xp + tt * 32 + quad * 8 + 4);
        bf16x8 f;
        f[0] = (__bf16)xa.x; f[1] = (__bf16)xa.y;
        f[2] = (__bf16)xa.z; f[3] = (__bf16)xa.w;
        f[4] = (__bf16)xb.x; f[5] = (__bf16)xb.y;
        f[6] = (__bf16)xb.z; f[7] = (__bf16)xb.w;
        af[tt] = f;
    }

    f32x4 acc[4], accA;
    #pragma unroll
    for (int cb = 0; cb < 4; ++cb) {
        acc[cb] = (f32x4){0.f, 0.f, 0.f, 0.f};
        #pragma unroll
        for (int tt = 0; tt < 4; ++tt)
            acc[cb] = __builtin_amdgcn_mfma_f32_16x16x32_bf16(
                af[tt], Wswz[(cb << 2) | tt][lane], acc[cb], 0, 0, 0);
    }
    accA = (f32x4){0.f, 0.f, 0.f, 0.f};
    #pragma unroll
    for (int tt = 0; tt < 4; ++tt)
        accA = __builtin_amdgcn_mfma_f32_16x16x32_bf16(
            af[tt], Wswz[16 + tt][lane], accA, 0, 0, 0);

    // h store: scalar bf16 per (cb,r)
    #pragma unroll
    for (int cb = 0; cb < 4; ++cb) {
        #pragma unroll
        for (int r = 0; r < 4; ++r) {
            int node = node_base + quad * 4 + r;
            if (node < N)
                h_out[node * 64 + cb * 16 + col] = (unsigned short)f2b(acc[cb][r]);
        }
    }
    // att store from accA: D col<4 -> att_s head=col, col 4..7 -> att_d
    if (col < 8) {
        #pragma unroll
        for (int r = 0; r < 4; ++r) {
            int node = node_base + quad * 4 + r;
            if (node < N) {
                if (col < 4) att_s_o[(node << 2) | col] = accA[r];
                else         att_d_o[(node << 2) | (col - 4)] = accA[r];
            }
        }
    }
}

// ---------------- K2: LDS-staged radix partition -> packed ints -----------
// Bucket bases computed locally from bucketCount (no bscan kernel);
// bucketCursor holds bucket-RELATIVE reserved offsets (memset 0).
__global__ __launch_bounds__(256) void bscatter_kernel(
    const int* __restrict__ src, const int* __restrict__ dst,
    const int* __restrict__ bucketCount,
    int* __restrict__ bucketCursor, int* __restrict__ pairs, int nb, int E)
{
    __shared__ int cnt[256], lo[256], gpos[256], cur[256], sm[256], gbc[256];
    __shared__ int2 staged[CH];        // .x = packed (s<<9|dloc), .y = bucket
    int t = threadIdx.x;
    int base = blockIdx.x * CH;
    int nloc = min(CH, E - base);

    cnt[t] = 0;
    gbc[t] = (t < nb) ? bucketCount[t] : 0;
    __syncthreads();
    for (int i = t; i < nloc; i += 256)
        atomicAdd(&cnt[dst[base + i] >> BSHIFT], 1);
    __syncthreads();

    int v = cnt[t];
    sm[t] = v;
    __syncthreads();
    #pragma unroll
    for (int off = 1; off < 256; off <<= 1) {
        int u = (t >= off) ? sm[t - off] : 0;
        __syncthreads();
        sm[t] += u;
        __syncthreads();
    }
    lo[t] = sm[t] - v;
    cur[t] = lo[t];
    __syncthreads();

    int g = gbc[t];
    sm[t] = g;
    __syncthreads();
    #pragma unroll
    for (int off = 1; off < 256; off <<= 1) {
        int u = (t >= off) ? sm[t - off] : 0;
        __syncthreads();
        sm[t] += u;
        __syncthreads();
    }
    gpos[t] = (v > 0) ? (sm[t] - g) + atomicAdd(&bucketCursor[t], v) : 0;
    __syncthreads();

    for (int i = t; i < nloc; i += 256) {
        int d = dst[base + i];
        int s = src[base + i];
        int b = d >> BSHIFT;
        int k = atomicAdd(&cur[b], 1);
        staged[k] = make_int2((s << BSHIFT) | (d & (BNODES - 1)), b);
    }
    __syncthreads();

    for (int i = t; i < nloc; i += 256) {
        int2 p = staged[i];
        pairs[gpos[p.y] + (i - lo[p.y])] = p.x;
    }
}

// ---------------- K3: per-bucket CSR fill (1024 threads/bucket) -----------
__global__ __launch_bounds__(1024) void csrfill_kernel(
    const int* __restrict__ pairs, const int* __restrict__ bucketCount,
    int* __restrict__ rowstart, int* __restrict__ elsrc, int nb, int N, int E)
{
    __shared__ int hist[512], cur[512], sm[512], gbc[256], gsm[256];
    int b = blockIdx.x, t = threadIdx.x;
    int node_lo = b << BSHIFT;
    int nn = min(BNODES, N - node_lo);

    if (t < 256) { gbc[t] = (t < nb) ? bucketCount[t] : 0; gsm[t] = gbc[t]; }
    if (t < 512) hist[t] = 0;
    __syncthreads();
    #pragma unroll
    for (int off = 1; off < 256; off <<= 1) {
        int u = (t >= off && t < 256) ? gsm[t - off] : 0;
        __syncthreads();
        if (t < 256) gsm[t] += u;
        __syncthreads();
    }
    int ebase = gsm[b] - gbc[b];
    int ecnt = gbc[b];

    for (int i = t; i < ecnt; i += 1024)
        atomicAdd(&hist[pairs[ebase + i] & (BNODES - 1)], 1);
    __syncthreads();

    int v = (t < 512) ? hist[t] : 0;
    if (t < 512) sm[t] = v;
    __syncthreads();
    #pragma unroll
    for (int off = 1; off < 512; off <<= 1) {
        int u = (t >= off && t < 512) ? sm[t - off] : 0;
        __syncthreads();
        if (t < 512) sm[t] += u;
        __syncthreads();
    }
    if (t < 512) {
        int excl = sm[t] - v;
        cur[t] = excl;
        if (t < nn) rowstart[node_lo + t] = ebase + excl;
    }
    if (b == gridDim.x - 1 && t == 0) rowstart[N] = E;
    __syncthreads();

    for (int i = t; i < ecnt; i += 1024) {
        int p = pairs[ebase + i];
        int k = atomicAdd(&cur[p & (BNODES - 1)], 1);
        elsrc[ebase + k] = p >> BSHIFT;
    }
}

// ---------------- K4: per-node aggregate, 8 edges/iteration ---------------
__global__ __launch_bounds__(256) void agg_kernel(
    const int* __restrict__ elsrc,           // [E]
    const int* __restrict__ rowstart,        // [N+1]
    const float* __restrict__ att_s,         // [N,4]
    const float* __restrict__ att_d,         // [N,4]
    const unsigned short* __restrict__ hmat, // bf16 [N,64]
    float* __restrict__ out,                 // [N,64]
    int N)
{
    int node = blockIdx.x * 4 + (threadIdx.x >> 6);
    if (node >= N) return;
    int lane = threadIdx.x & 63;
    int q = lane & 7;        // feature octet
    int eslot = lane >> 3;   // 0..7
    int h = q >> 1;          // head

    int beg = rowstart[node];
    int deg = rowstart[node + 1] - beg;
    float ad = att_d[(node << 2) | h];

    float a0 = 0.f, a1 = 0.f, a2 = 0.f, a3 = 0.f;
    float a4 = 0.f, a5 = 0.f, a6 = 0.f, a7 = 0.f, l = 0.f;

    for (int base = 0; base < deg; base += 8) {
        int e = base + eslot;
        int idx = beg + min(e, deg - 1);
        int s = elsrc[idx];
        float av = att_s[(s << 2) | h] + ad;
        av = fmaxf(av, NEG_SLOPE * av);
        float w = (e < deg) ? __expf(av) : 0.f;
        l += w;
        uint4 hp = *(const uint4*)(hmat + (s << 6) + (q << 3));
        a0 = fmaf(w, u2f(hp.x << 16), a0);
        a1 = fmaf(w, u2f(hp.x & 0xffff0000u), a1);
        a2 = fmaf(w, u2f(hp.y << 16), a2);
        a3 = fmaf(w, u2f(hp.y & 0xffff0000u), a3);
        a4 = fmaf(w, u2f(hp.z << 16), a4);
        a5 = fmaf(w, u2f(hp.z & 0xffff0000u), a5);
        a6 = fmaf(w, u2f(hp.w << 16), a6);
        a7 = fmaf(w, u2f(hp.w & 0xffff0000u), a7);
    }

    #pragma unroll
    for (int m = 8; m <= 32; m <<= 1) {
        a0 += __shfl_xor(a0, m, 64);
        a1 += __shfl_xor(a1, m, 64);
        a2 += __shfl_xor(a2, m, 64);
        a3 += __shfl_xor(a3, m, 64);
        a4 += __shfl_xor(a4, m, 64);
        a5 += __shfl_xor(a5, m, 64);
        a6 += __shfl_xor(a6, m, 64);
        a7 += __shfl_xor(a7, m, 64);
        l  += __shfl_xor(l,  m, 64);
    }

    if (eslot == 0) {
        float rl = 1.0f / (l + 1e-16f);
        float4 v0, v1;
        v0.x = a0 * rl; v0.x = (v0.x > 0.f) ? v0.x : (__expf(v0.x) - 1.f);
        v0.y = a1 * rl; v0.y = (v0.y > 0.f) ? v0.y : (__expf(v0.y) - 1.f);
        v0.z = a2 * rl; v0.z = (v0.z > 0.f) ? v0.z : (__expf(v0.z) - 1.f);
        v0.w = a3 * rl; v0.w = (v0.w > 0.f) ? v0.w : (__expf(v0.w) - 1.f);
        v1.x = a4 * rl; v1.x = (v1.x > 0.f) ? v1.x : (__expf(v1.x) - 1.f);
        v1.y = a5 * rl; v1.y = (v1.y > 0.f) ? v1.y : (__expf(v1.y) - 1.f);
        v1.z = a6 * rl; v1.z = (v1.z > 0.f) ? v1.z : (__expf(v1.z) - 1.f);
        v1.w = a7 * rl; v1.w = (v1.w > 0.f) ? v1.w : (__expf(v1.w) - 1.f);
        float* op = out + (node << 6) + (q << 3);
        *(float4*)op = v0;
        *(float4*)(op + 4) = v1;
    }
}

extern "C" void kernel_launch(void* const* d_in, const int* in_sizes, int n_in,
                              void* d_out, int out_size, void* d_ws, size_t ws_size,
                              hipStream_t stream) {
    const float* x     = (const float*)d_in[0];
    const int*   ei    = (const int*)d_in[1];
    const float* W     = (const float*)d_in[2];
    const float* a_src = (const float*)d_in[3];
    const float* a_dst = (const float*)d_in[4];

    int N = in_sizes[0] / 128;
    int E = in_sizes[1] / 2;
    const int* src = ei;
    const int* dst = ei + E;
    int nb = (N + BNODES - 1) / BNODES;       // 196 buckets

    char* ws = (char*)d_ws;
    size_t off = 0;
    unsigned short* hmat = (unsigned short*)(ws + off); off += (size_t)N * 64 * 2; // 12.8 MB
    float* att_s = (float*)(ws + off);  off += (size_t)N * 4 * 4;
    float* att_d = (float*)(ws + off);  off += (size_t)N * 4 * 4;
    int* rowstart = (int*)(ws + off);   off += (size_t)(N + 1) * 4;
    int* elsrc    = (int*)(ws + off);   off += (size_t)E * 4;        // 6.4 MB
    int* pairs    = (int*)(ws + off);   off += (size_t)E * 4;        // 6.4 MB
    int* bucketCount  = (int*)(ws + off); off += 256 * 4;            // zeroed
    int* bucketCursor = (int*)(ws + off); off += 256 * 4;            // zeroed

    hipMemsetAsync(bucketCount, 0, 512 * 4, stream);

    int gemmBlocks = (N + 63) / 64;           // 1563
    gemm_att_kernel<<<gemmBlocks + BCB, 256, 0, stream>>>(
        x, W, a_src, a_dst, hmat, att_s, att_d, dst, bucketCount,
        N, E, gemmBlocks);

    int blocksS = (E + CH - 1) / CH;          // 782
    bscatter_kernel<<<blocksS, 256, 0, stream>>>(src, dst, bucketCount,
                                                 bucketCursor, pairs, nb, E);

    csrfill_kernel<<<nb, 1024, 0, stream>>>(pairs, bucketCount,
                                            rowstart, elsrc, nb, N, E);

    int blocksA = (N + 3) / 4;
    agg_kernel<<<blocksA, 256, 0, stream>>>(elsrc, rowstart, att_s, att_d,
                                            hmat, (float*)d_out, N);
}